// Round 8
// baseline (3694.991 us; speedup 1.0000x reference)
//
#include <hip/hip_runtime.h>
#include <cstdint>
#include <cstddef>

// SNN forward, fp32-faithful (r4/r6 passing semantics, bitwise-identical
// summation order per output). Round 8 = round 7 structure (1024-thread
// cross-step pipeline: FC(t) || conv1(t+1), out(t-1) || x-staging) with the
// ONE fix: __launch_bounds__(1024) (no min-blocks arg). r7's (1024,4) made
// the compiler cap VGPRs at 64 -> per-thread LIF state spilled to scratch
// (5 GB HBM traffic/dispatch). 16 waves/block already implies a 128-VGPR
// cap, which was spill-free in r6 with the same per-thread footprint.

#define TSTEPS 64
#define NB 256

__global__ __launch_bounds__(256)
void transpose_wfc(const float* __restrict__ wfc, float* __restrict__ wfcT) {
    int idx = blockIdx.x * 256 + threadIdx.x;     // [500,800] -> [800,500]
    if (idx < 500 * 800) {
        int o = idx / 800, j = idx % 800;
        wfcT[j * 500 + o] = wfc[idx];
    }
}

__global__ __launch_bounds__(256)
void pad_w2(const float* __restrict__ w2, float* __restrict__ w2r) {
    int idx = blockIdx.x * 256 + threadIdx.x;     // [50,20,5,5] -> [20,5,50,8]
    if (idx < 20 * 5 * 50 * 8) {
        int kc = idx & 7;
        int oc = (idx >> 3) % 50;
        int kr = (idx >> 3) / 50 % 5;
        int ic = (idx >> 3) / 250;
        w2r[idx] = (kc < 5) ? w2[((oc * 20 + ic) * 5 + kr) * 5 + kc] : 0.f;
    }
}

__global__ __launch_bounds__(1024)
void snn_forward(const float* __restrict__ x,      // [64,256,1,28,28]
                 const float* __restrict__ w1,     // [20,1,5,5]
                 const float* __restrict__ b1,     // [20]
                 const float* __restrict__ w2,     // [50,20,5,5]
                 const float* __restrict__ w2r,    // [20,5,50,8] padded (or null)
                 const float* __restrict__ b2,     // [50]
                 const float* __restrict__ fcw,    // wfcT [800,500] or wfc [500,800]
                 long fc_sj, long fc_so,
                 const float* __restrict__ bfc,    // [500]
                 const float* __restrict__ wout,   // [10,500]
                 float* __restrict__ out)          // [64,256,10]
{
    const float CM = 0.1f;
    const float CS = 0.8f;

    const int b   = blockIdx.x;
    const int tid = threadIdx.x;

    // ---- LDS (~29 KB) ----
    __shared__ float xs[2][28 * 36];                 // double-buffered input tile
    __shared__ float p1[20 * 12 * 12];               // pooled L1 spikes, 0.0/1.0
    __shared__ float w1L[500];                       // conv1 weights
    __shared__ unsigned int flagbits[20];            // 12 pooled-row flags per ic
    __shared__ unsigned int bm2[25];                 // pooled-L2 bitmap (800 bits)
    __shared__ unsigned int bm3[16];                 // L3 bitmap (500 bits)
    __shared__ unsigned short list2s[800];           // active fc-input indices (asc)
    __shared__ unsigned short list3s[500];           // active L3 indices (asc)
    __shared__ float v2s[500], i2s[500];             // L3 LIF state
    __shared__ float vos[10],  ios[10];              // output LI state
    __shared__ int nn2s, nn3s;

    // ---- one-time init ----
    if (tid < 500) { v2s[tid] = 0.f; i2s[tid] = 0.f; w1L[tid] = w1[tid]; }
    if (tid < 10)  { vos[tid] = 0.f; ios[tid] = 0.f; }
    if (tid < 20)  flagbits[tid] = 0u;
    if (tid >= 32 && tid < 57) bm2[tid - 32] = 0u;
    if (tid >= 64 && tid < 80) bm3[tid - 64] = 0u;

    // staging map: threads 0..391, elements tid and tid+392
    const int stg = (tid < 392);
    const int sa0 = tid / 28,         sb0 = tid - sa0 * 28;
    const int sa1 = (tid + 392) / 28, sb1 = (tid + 392) - sa1 * 28;

    // ---- conv1 mapping: threads 512..991 = 20 ch x 12 pool-rows x 2 halves ----
    const int t1  = tid - 512;
    const int l1  = (tid >= 512 && tid < 992);
    const int c   = t1 / 24;
    const int sub = t1 % 24;
    const int pr  = sub >> 1;
    const int chh = sub & 1;
    const int r0  = pr * 2;
    const int c0  = chh * 12;
    float v0a[12], v0b[12], i0a[12], i0b[12];        // L1 state (conv1 threads)
    #pragma unroll
    for (int j = 0; j < 12; ++j) { v0a[j] = 0.f; v0b[j] = 0.f; i0a[j] = 0.f; i0b[j] = 0.f; }
    const float bias1 = (l1 && c < 20) ? b1[c] : 0.f;

    // ---- conv2 mapping: threads 0..399 = 50 oc x 8 rows; 8 cols each ----
    const int l2  = (tid < 400);
    const int oc2 = tid >> 3;
    const int y2  = tid & 7;
    float v1r[8], i1r[8];
    #pragma unroll
    for (int j = 0; j < 8; ++j) { v1r[j] = 0.f; i1r[j] = 0.f; }
    const float bias2 = l2 ? b2[oc2] : 0.f;

    // prologue: stage x(0) into xs[0]
    if (stg) {
        const float* xp = x + (size_t)b * 784;
        xs[0][sa0 * 36 + sb0] = xp[tid];
        xs[0][sa1 * 36 + sb1] = xp[tid + 392];
    }
    __syncthreads();

    // conv1 body over step u (reads xs[u&1], updates L1 state, writes p1 +
    // flagbits). Bitwise-identical order to r4/r6.
    auto conv1_step = [&](int u) {
        float acc0[12], acc1[12];
        #pragma unroll
        for (int j = 0; j < 12; ++j) { acc0[j] = 0.f; acc1[j] = 0.f; }
        float wc[5], wp[5];
        const float* xb = xs[u & 1];
        #pragma unroll
        for (int ir = 0; ir < 6; ++ir) {
            float xr[16];
            const float4* rp = (const float4*)(xb + (r0 + ir) * 36 + c0);
            #pragma unroll
            for (int q = 0; q < 4; ++q) {
                float4 f = rp[q];
                xr[4*q+0] = f.x; xr[4*q+1] = f.y; xr[4*q+2] = f.z; xr[4*q+3] = f.w;
            }
            if (ir < 5) {
                #pragma unroll
                for (int k = 0; k < 5; ++k) wc[k] = w1L[c * 25 + ir * 5 + k];
                #pragma unroll
                for (int kc = 0; kc < 5; ++kc) {
                    const float w = wc[kc];
                    #pragma unroll
                    for (int j = 0; j < 12; ++j)
                        acc0[j] = __fmaf_rn(w, xr[j + kc], acc0[j]);
                }
            }
            if (ir >= 1) {
                #pragma unroll
                for (int kc = 0; kc < 5; ++kc) {
                    const float w = wp[kc];
                    #pragma unroll
                    for (int j = 0; j < 12; ++j)
                        acc1[j] = __fmaf_rn(w, xr[j + kc], acc1[j]);
                }
            }
            #pragma unroll
            for (int k = 0; k < 5; ++k) wp[k] = wc[k];
        }
        unsigned int zb0 = 0, zb1 = 0;
        #pragma unroll
        for (int j = 0; j < 12; ++j) {
            const float inp = __fadd_rn(acc0[j], bias1);
            const float vd  = __fadd_rn(v0a[j], __fmul_rn(CM, __fsub_rn(i0a[j], v0a[j])));
            const float id  = __fmul_rn(i0a[j], CS);
            const int z = (__fsub_rn(vd, 1.0f) > 0.0f);
            v0a[j] = z ? 0.f : vd;
            i0a[j] = __fadd_rn(id, inp);
            zb0 |= (unsigned)z << j;
        }
        #pragma unroll
        for (int j = 0; j < 12; ++j) {
            const float inp = __fadd_rn(acc1[j], bias1);
            const float vd  = __fadd_rn(v0b[j], __fmul_rn(CM, __fsub_rn(i0b[j], v0b[j])));
            const float id  = __fmul_rn(i0b[j], CS);
            const int z = (__fsub_rn(vd, 1.0f) > 0.0f);
            v0b[j] = z ? 0.f : vd;
            i0b[j] = __fadd_rn(id, inp);
            zb1 |= (unsigned)z << j;
        }
        const unsigned int zp = zb0 | zb1;
        #pragma unroll
        for (int jj = 0; jj < 6; ++jj)
            p1[(c * 12 + pr) * 12 + chh * 6 + jj] = ((zp >> (2 * jj)) & 3u) ? 1.0f : 0.0f;
        if (zp) atomicOr(&flagbits[c], 1u << pr);
    };

    // prologue: conv1(0)
    if (l1) conv1_step(0);
    __syncthreads();

    for (int ts = 0; ts < TSTEPS; ++ts) {
        // ===== stage1: stage x(ts+1) | out(ts-1) | bm3 reset =====
        if (stg) {
            if (ts + 1 < TSTEPS) {
                const float* xp = x + ((size_t)(ts + 1) * NB + b) * 784;
                float a = xp[tid], bb2_ = xp[tid + 392];
                float* xd = xs[(ts + 1) & 1];
                xd[sa0 * 36 + sb0] = a;
                xd[sa1 * 36 + sb1] = bb2_;
            }
        } else if (tid >= 992 && tid < 1002) {
            if (ts > 0) {
                const int o = tid - 992;
                const int nn3 = nn3s;
                float acc = 0.f;
                int k = 0;
                for (; k + 3 < nn3; k += 4) {
                    const int j0 = list3s[k],     j1 = list3s[k + 1];
                    const int j2 = list3s[k + 2], j3 = list3s[k + 3];
                    const float a0 = wout[o * 500 + j0];
                    const float a1 = wout[o * 500 + j1];
                    const float a2 = wout[o * 500 + j2];
                    const float a3 = wout[o * 500 + j3];
                    acc = __fmaf_rn(1.0f, a0, acc); acc = __fmaf_rn(1.0f, a1, acc);
                    acc = __fmaf_rn(1.0f, a2, acc); acc = __fmaf_rn(1.0f, a3, acc);
                }
                for (; k < nn3; ++k)
                    acc = __fmaf_rn(1.0f, wout[o * 500 + list3s[k]], acc);
                const float vn = __fadd_rn(vos[o], __fmul_rn(CM, __fsub_rn(ios[o], vos[o])));
                ios[o] = __fadd_rn(__fmul_rn(ios[o], CS), acc);
                vos[o] = vn;
                out[((size_t)(ts - 1) * NB + b) * 10 + o] = vn;
            }
        } else if (tid >= 1002 && tid < 1018) {
            bm3[tid - 1002] = 0u;
        }
        __syncthreads();   // (B)

        // ===== stage2: conv2(ts) + LIF2 -> bm2 =====
        if (l2) {
            float acc[8];
            #pragma unroll
            for (int xx = 0; xx < 8; ++xx) acc[xx] = 0.f;
            for (int ic = 0; ic < 20; ++ic) {
                const unsigned int win = (flagbits[ic] >> y2) & 31u;
                if (!win) continue;
                #pragma unroll
                for (int kr = 0; kr < 5; ++kr) {
                    if (!(win & (1u << kr))) continue;
                    const float4* pp = (const float4*)(p1 + (ic * 12 + y2 + kr) * 12);
                    float4 f0 = pp[0], f1 = pp[1], f2 = pp[2];
                    const float pv[12] = { f0.x,f0.y,f0.z,f0.w, f1.x,f1.y,f1.z,f1.w, f2.x,f2.y,f2.z,f2.w };
                    float w0, w1_, w2_, w3_, w4_;
                    if (w2r) {
                        const float* wr = w2r + ((ic * 5 + kr) * 50 + oc2) * 8;
                        const float4 wv = *(const float4*)wr;
                        w0 = wv.x; w1_ = wv.y; w2_ = wv.z; w3_ = wv.w; w4_ = wr[4];
                    } else {
                        const float* wrow = w2 + ((oc2 * 20 + ic) * 5 + kr) * 5;
                        w0 = wrow[0]; w1_ = wrow[1]; w2_ = wrow[2]; w3_ = wrow[3]; w4_ = wrow[4];
                    }
                    #pragma unroll
                    for (int xx = 0; xx < 8; ++xx) acc[xx] = __fmaf_rn(w0, pv[xx],     acc[xx]);
                    #pragma unroll
                    for (int xx = 0; xx < 8; ++xx) acc[xx] = __fmaf_rn(w1_, pv[xx + 1], acc[xx]);
                    #pragma unroll
                    for (int xx = 0; xx < 8; ++xx) acc[xx] = __fmaf_rn(w2_, pv[xx + 2], acc[xx]);
                    #pragma unroll
                    for (int xx = 0; xx < 8; ++xx) acc[xx] = __fmaf_rn(w3_, pv[xx + 3], acc[xx]);
                    #pragma unroll
                    for (int xx = 0; xx < 8; ++xx) acc[xx] = __fmaf_rn(w4_, pv[xx + 4], acc[xx]);
                }
            }
            unsigned int pb = 0;
            const unsigned int bitbase = (unsigned)((oc2 & 1) * 16 + (y2 >> 1) * 4);
            #pragma unroll
            for (int xx = 0; xx < 8; ++xx) {
                const float inp = __fmul_rn(10.0f, __fadd_rn(acc[xx], bias2));
                const float vd  = __fadd_rn(v1r[xx], __fmul_rn(CM, __fsub_rn(i1r[xx], v1r[xx])));
                const float id  = __fmul_rn(i1r[xx], CS);
                const int z = (__fsub_rn(vd, 1.0f) > 0.0f);
                v1r[xx] = z ? 0.f : vd;
                i1r[xx] = __fadd_rn(id, inp);
                if (z) pb |= 1u << (bitbase + (xx >> 1));
            }
            if (pb) atomicOr(&bm2[oc2 >> 1], pb);
        }
        __syncthreads();   // (C)

        // ===== stage3: scan2 + list2 (asc) | flagbits reset =====
        if (tid < 25) {
            int off = 0;
            for (int w = 0; w < 25; ++w) if (w < tid) off += __popc(bm2[w]);
            unsigned int bits = bm2[tid];
            if (tid == 24) nn2s = off + __popc(bits);
            while (bits) {
                const int bb = __builtin_ctz(bits);
                bits &= bits - 1;
                list2s[off++] = (unsigned short)(tid * 32 + bb);
            }
        } else if (tid >= 32 && tid < 52) {
            flagbits[tid - 32] = 0u;
        }
        __syncthreads();   // (D)

        // ===== stage4: FC(ts)+LIF3 [0..499]  ||  conv1(ts+1) [512..991]  ||  bm2 reset =====
        if (tid < 500) {
            const int nn2 = nn2s;
            const long obase = (long)tid * fc_so;
            float acc = 0.f;
            int k = 0;
            for (; k + 15 < nn2; k += 16) {
                float a[16];
                #pragma unroll
                for (int q = 0; q < 16; ++q)
                    a[q] = fcw[(long)list2s[k + q] * fc_sj + obase];
                #pragma unroll
                for (int q = 0; q < 16; ++q)
                    acc = __fmaf_rn(1.0f, a[q], acc);
            }
            for (; k < nn2; ++k)
                acc = __fmaf_rn(1.0f, fcw[(long)list2s[k] * fc_sj + obase], acc);
            const float inp = __fadd_rn(acc, bfc[tid]);
            const float vd  = __fadd_rn(v2s[tid], __fmul_rn(CM, __fsub_rn(i2s[tid], v2s[tid])));
            const float id  = __fmul_rn(i2s[tid], CS);
            const int z = (__fsub_rn(vd, 1.0f) > 0.0f);
            v2s[tid] = z ? 0.f : vd;
            i2s[tid] = __fadd_rn(id, inp);
            if (z) atomicOr(&bm3[tid >> 5], 1u << (tid & 31));
        } else if (l1) {
            if (ts + 1 < TSTEPS) conv1_step(ts + 1);
        } else if (tid >= 999 && tid < 1024) {
            bm2[tid - 999] = 0u;
        }
        __syncthreads();   // (E)

        // ===== stage5: scan3 + list3 (asc) =====
        if (tid < 16) {
            int off = 0;
            for (int w = 0; w < 16; ++w) if (w < tid) off += __popc(bm3[w]);
            unsigned int bits = bm3[tid];
            if (tid == 15) nn3s = off + __popc(bits);
            while (bits) {
                const int bb = __builtin_ctz(bits);
                bits &= bits - 1;
                list3s[off++] = (unsigned short)(tid * 32 + bb);
            }
        }
        __syncthreads();   // (F)
    }

    // epilogue: out(63)
    if (tid >= 992 && tid < 1002) {
        const int o = tid - 992;
        const int nn3 = nn3s;
        float acc = 0.f;
        int k = 0;
        for (; k + 3 < nn3; k += 4) {
            const int j0 = list3s[k],     j1 = list3s[k + 1];
            const int j2 = list3s[k + 2], j3 = list3s[k + 3];
            const float a0 = wout[o * 500 + j0];
            const float a1 = wout[o * 500 + j1];
            const float a2 = wout[o * 500 + j2];
            const float a3 = wout[o * 500 + j3];
            acc = __fmaf_rn(1.0f, a0, acc); acc = __fmaf_rn(1.0f, a1, acc);
            acc = __fmaf_rn(1.0f, a2, acc); acc = __fmaf_rn(1.0f, a3, acc);
        }
        for (; k < nn3; ++k)
            acc = __fmaf_rn(1.0f, wout[o * 500 + list3s[k]], acc);
        const float vn = __fadd_rn(vos[o], __fmul_rn(CM, __fsub_rn(ios[o], vos[o])));
        vos[o] = vn;  // ios update unnecessary (last step)
        out[((size_t)(TSTEPS - 1) * NB + b) * 10 + o] = vn;
    }
}

extern "C" void kernel_launch(void* const* d_in, const int* in_sizes, int n_in,
                              void* d_out, int out_size, void* d_ws, size_t ws_size,
                              hipStream_t stream)
{
    const float* x    = (const float*)d_in[0];
    const float* w1   = (const float*)d_in[1];
    const float* b1   = (const float*)d_in[2];
    const float* w2   = (const float*)d_in[3];
    const float* b2   = (const float*)d_in[4];
    const float* wfc  = (const float*)d_in[5];
    const float* bfc  = (const float*)d_in[6];
    const float* wout = (const float*)d_in[7];
    float* out = (float*)d_out;

    const size_t szT  = (size_t)500 * 800 * sizeof(float);       // 1.6 MB
    const size_t szW2 = (size_t)20 * 5 * 50 * 8 * sizeof(float); // 160 KB

    const float* fcptr = wfc;
    long sj = 1, so = 800;
    const float* w2rp = nullptr;
    if (ws_size >= szT) {
        float* wfcT = (float*)d_ws;
        transpose_wfc<<<(500 * 800 + 255) / 256, 256, 0, stream>>>(wfc, wfcT);
        fcptr = wfcT; sj = 500; so = 1;
        if (ws_size >= szT + szW2) {
            float* w2pad = (float*)((char*)d_ws + szT);
            pad_w2<<<(20 * 5 * 50 * 8 + 255) / 256, 256, 0, stream>>>(w2, w2pad);
            w2rp = w2pad;
        }
    }

    snn_forward<<<NB, 1024, 0, stream>>>(x, w1, b1, w2, w2rp, b2,
                                         fcptr, sj, so, bfc, wout, out);
}

// Round 9
// 3682.077 us; speedup vs baseline: 1.0035x; 1.0035x over previous
//
#include <hip/hip_runtime.h>
#include <cstdint>
#include <cstddef>

// SNN forward, fp32-faithful (r4/r6 passing semantics, bitwise-identical
// summation order per output). Round 9 = round 7/8 structure (1024-thread
// cross-step pipeline: FC(t) || conv1(t+1), out(t-1) || x-staging) with
// __launch_bounds__(1024, 1): this toolchain treats the 2nd arg as min
// BLOCKS per CU (evidence: (512,2)->128 VGPR cap, (1024,4)/(1024)->64).
// min-blocks=1 -> 16 waves/CU -> 4 waves/EU -> 128-VGPR cap, spill-free
// (r7/r8 at 64 VGPR spilled 5 GB/dispatch to scratch).

#define TSTEPS 64
#define NB 256

__global__ __launch_bounds__(256)
void transpose_wfc(const float* __restrict__ wfc, float* __restrict__ wfcT) {
    int idx = blockIdx.x * 256 + threadIdx.x;     // [500,800] -> [800,500]
    if (idx < 500 * 800) {
        int o = idx / 800, j = idx % 800;
        wfcT[j * 500 + o] = wfc[idx];
    }
}

__global__ __launch_bounds__(256)
void pad_w2(const float* __restrict__ w2, float* __restrict__ w2r) {
    int idx = blockIdx.x * 256 + threadIdx.x;     // [50,20,5,5] -> [20,5,50,8]
    if (idx < 20 * 5 * 50 * 8) {
        int kc = idx & 7;
        int oc = (idx >> 3) % 50;
        int kr = (idx >> 3) / 50 % 5;
        int ic = (idx >> 3) / 250;
        w2r[idx] = (kc < 5) ? w2[((oc * 20 + ic) * 5 + kr) * 5 + kc] : 0.f;
    }
}

__global__ __launch_bounds__(1024, 1)
void snn_forward(const float* __restrict__ x,      // [64,256,1,28,28]
                 const float* __restrict__ w1,     // [20,1,5,5]
                 const float* __restrict__ b1,     // [20]
                 const float* __restrict__ w2,     // [50,20,5,5]
                 const float* __restrict__ w2r,    // [20,5,50,8] padded (or null)
                 const float* __restrict__ b2,     // [50]
                 const float* __restrict__ fcw,    // wfcT [800,500] or wfc [500,800]
                 long fc_sj, long fc_so,
                 const float* __restrict__ bfc,    // [500]
                 const float* __restrict__ wout,   // [10,500]
                 float* __restrict__ out)          // [64,256,10]
{
    const float CM = 0.1f;
    const float CS = 0.8f;

    const int b   = blockIdx.x;
    const int tid = threadIdx.x;

    // ---- LDS (~29 KB) ----
    __shared__ float xs[2][28 * 36];                 // double-buffered input tile
    __shared__ float p1[20 * 12 * 12];               // pooled L1 spikes, 0.0/1.0
    __shared__ float w1L[500];                       // conv1 weights
    __shared__ unsigned int flagbits[20];            // 12 pooled-row flags per ic
    __shared__ unsigned int bm2[25];                 // pooled-L2 bitmap (800 bits)
    __shared__ unsigned int bm3[16];                 // L3 bitmap (500 bits)
    __shared__ unsigned short list2s[800];           // active fc-input indices (asc)
    __shared__ unsigned short list3s[500];           // active L3 indices (asc)
    __shared__ float v2s[500], i2s[500];             // L3 LIF state
    __shared__ float vos[10],  ios[10];              // output LI state
    __shared__ int nn2s, nn3s;

    // ---- one-time init ----
    if (tid < 500) { v2s[tid] = 0.f; i2s[tid] = 0.f; w1L[tid] = w1[tid]; }
    if (tid < 10)  { vos[tid] = 0.f; ios[tid] = 0.f; }
    if (tid < 20)  flagbits[tid] = 0u;
    if (tid >= 32 && tid < 57) bm2[tid - 32] = 0u;
    if (tid >= 64 && tid < 80) bm3[tid - 64] = 0u;

    // staging map: threads 0..391, elements tid and tid+392
    const int stg = (tid < 392);
    const int sa0 = tid / 28,         sb0 = tid - sa0 * 28;
    const int sa1 = (tid + 392) / 28, sb1 = (tid + 392) - sa1 * 28;

    // ---- conv1 mapping: threads 512..991 = 20 ch x 12 pool-rows x 2 halves ----
    const int t1  = tid - 512;
    const int l1  = (tid >= 512 && tid < 992);
    const int c   = t1 / 24;
    const int sub = t1 % 24;
    const int pr  = sub >> 1;
    const int chh = sub & 1;
    const int r0  = pr * 2;
    const int c0  = chh * 12;
    float v0a[12], v0b[12], i0a[12], i0b[12];        // L1 state (conv1 threads)
    #pragma unroll
    for (int j = 0; j < 12; ++j) { v0a[j] = 0.f; v0b[j] = 0.f; i0a[j] = 0.f; i0b[j] = 0.f; }
    const float bias1 = (l1 && c < 20) ? b1[c] : 0.f;

    // ---- conv2 mapping: threads 0..399 = 50 oc x 8 rows; 8 cols each ----
    const int l2  = (tid < 400);
    const int oc2 = tid >> 3;
    const int y2  = tid & 7;
    float v1r[8], i1r[8];
    #pragma unroll
    for (int j = 0; j < 8; ++j) { v1r[j] = 0.f; i1r[j] = 0.f; }
    const float bias2 = l2 ? b2[oc2] : 0.f;

    // prologue: stage x(0) into xs[0]
    if (stg) {
        const float* xp = x + (size_t)b * 784;
        xs[0][sa0 * 36 + sb0] = xp[tid];
        xs[0][sa1 * 36 + sb1] = xp[tid + 392];
    }
    __syncthreads();

    // conv1 body over step u (reads xs[u&1], updates L1 state, writes p1 +
    // flagbits). Bitwise-identical order to r4/r6.
    auto conv1_step = [&](int u) {
        float acc0[12], acc1[12];
        #pragma unroll
        for (int j = 0; j < 12; ++j) { acc0[j] = 0.f; acc1[j] = 0.f; }
        float wc[5], wp[5];
        const float* xb = xs[u & 1];
        #pragma unroll
        for (int ir = 0; ir < 6; ++ir) {
            float xr[16];
            const float4* rp = (const float4*)(xb + (r0 + ir) * 36 + c0);
            #pragma unroll
            for (int q = 0; q < 4; ++q) {
                float4 f = rp[q];
                xr[4*q+0] = f.x; xr[4*q+1] = f.y; xr[4*q+2] = f.z; xr[4*q+3] = f.w;
            }
            if (ir < 5) {
                #pragma unroll
                for (int k = 0; k < 5; ++k) wc[k] = w1L[c * 25 + ir * 5 + k];
                #pragma unroll
                for (int kc = 0; kc < 5; ++kc) {
                    const float w = wc[kc];
                    #pragma unroll
                    for (int j = 0; j < 12; ++j)
                        acc0[j] = __fmaf_rn(w, xr[j + kc], acc0[j]);
                }
            }
            if (ir >= 1) {
                #pragma unroll
                for (int kc = 0; kc < 5; ++kc) {
                    const float w = wp[kc];
                    #pragma unroll
                    for (int j = 0; j < 12; ++j)
                        acc1[j] = __fmaf_rn(w, xr[j + kc], acc1[j]);
                }
            }
            #pragma unroll
            for (int k = 0; k < 5; ++k) wp[k] = wc[k];
        }
        unsigned int zb0 = 0, zb1 = 0;
        #pragma unroll
        for (int j = 0; j < 12; ++j) {
            const float inp = __fadd_rn(acc0[j], bias1);
            const float vd  = __fadd_rn(v0a[j], __fmul_rn(CM, __fsub_rn(i0a[j], v0a[j])));
            const float id  = __fmul_rn(i0a[j], CS);
            const int z = (__fsub_rn(vd, 1.0f) > 0.0f);
            v0a[j] = z ? 0.f : vd;
            i0a[j] = __fadd_rn(id, inp);
            zb0 |= (unsigned)z << j;
        }
        #pragma unroll
        for (int j = 0; j < 12; ++j) {
            const float inp = __fadd_rn(acc1[j], bias1);
            const float vd  = __fadd_rn(v0b[j], __fmul_rn(CM, __fsub_rn(i0b[j], v0b[j])));
            const float id  = __fmul_rn(i0b[j], CS);
            const int z = (__fsub_rn(vd, 1.0f) > 0.0f);
            v0b[j] = z ? 0.f : vd;
            i0b[j] = __fadd_rn(id, inp);
            zb1 |= (unsigned)z << j;
        }
        const unsigned int zp = zb0 | zb1;
        #pragma unroll
        for (int jj = 0; jj < 6; ++jj)
            p1[(c * 12 + pr) * 12 + chh * 6 + jj] = ((zp >> (2 * jj)) & 3u) ? 1.0f : 0.0f;
        if (zp) atomicOr(&flagbits[c], 1u << pr);
    };

    // prologue: conv1(0)
    if (l1) conv1_step(0);
    __syncthreads();

    for (int ts = 0; ts < TSTEPS; ++ts) {
        // ===== stage1: stage x(ts+1) | out(ts-1) | bm3 reset =====
        if (stg) {
            if (ts + 1 < TSTEPS) {
                const float* xp = x + ((size_t)(ts + 1) * NB + b) * 784;
                float a = xp[tid], bb2_ = xp[tid + 392];
                float* xd = xs[(ts + 1) & 1];
                xd[sa0 * 36 + sb0] = a;
                xd[sa1 * 36 + sb1] = bb2_;
            }
        } else if (tid >= 992 && tid < 1002) {
            if (ts > 0) {
                const int o = tid - 992;
                const int nn3 = nn3s;
                float acc = 0.f;
                int k = 0;
                for (; k + 3 < nn3; k += 4) {
                    const int j0 = list3s[k],     j1 = list3s[k + 1];
                    const int j2 = list3s[k + 2], j3 = list3s[k + 3];
                    const float a0 = wout[o * 500 + j0];
                    const float a1 = wout[o * 500 + j1];
                    const float a2 = wout[o * 500 + j2];
                    const float a3 = wout[o * 500 + j3];
                    acc = __fmaf_rn(1.0f, a0, acc); acc = __fmaf_rn(1.0f, a1, acc);
                    acc = __fmaf_rn(1.0f, a2, acc); acc = __fmaf_rn(1.0f, a3, acc);
                }
                for (; k < nn3; ++k)
                    acc = __fmaf_rn(1.0f, wout[o * 500 + list3s[k]], acc);
                const float vn = __fadd_rn(vos[o], __fmul_rn(CM, __fsub_rn(ios[o], vos[o])));
                ios[o] = __fadd_rn(__fmul_rn(ios[o], CS), acc);
                vos[o] = vn;
                out[((size_t)(ts - 1) * NB + b) * 10 + o] = vn;
            }
        } else if (tid >= 1002 && tid < 1018) {
            bm3[tid - 1002] = 0u;
        }
        __syncthreads();   // (B)

        // ===== stage2: conv2(ts) + LIF2 -> bm2 =====
        if (l2) {
            float acc[8];
            #pragma unroll
            for (int xx = 0; xx < 8; ++xx) acc[xx] = 0.f;
            for (int ic = 0; ic < 20; ++ic) {
                const unsigned int win = (flagbits[ic] >> y2) & 31u;
                if (!win) continue;
                #pragma unroll
                for (int kr = 0; kr < 5; ++kr) {
                    if (!(win & (1u << kr))) continue;
                    const float4* pp = (const float4*)(p1 + (ic * 12 + y2 + kr) * 12);
                    float4 f0 = pp[0], f1 = pp[1], f2 = pp[2];
                    const float pv[12] = { f0.x,f0.y,f0.z,f0.w, f1.x,f1.y,f1.z,f1.w, f2.x,f2.y,f2.z,f2.w };
                    float w0, w1_, w2_, w3_, w4_;
                    if (w2r) {
                        const float* wr = w2r + ((ic * 5 + kr) * 50 + oc2) * 8;
                        const float4 wv = *(const float4*)wr;
                        w0 = wv.x; w1_ = wv.y; w2_ = wv.z; w3_ = wv.w; w4_ = wr[4];
                    } else {
                        const float* wrow = w2 + ((oc2 * 20 + ic) * 5 + kr) * 5;
                        w0 = wrow[0]; w1_ = wrow[1]; w2_ = wrow[2]; w3_ = wrow[3]; w4_ = wrow[4];
                    }
                    #pragma unroll
                    for (int xx = 0; xx < 8; ++xx) acc[xx] = __fmaf_rn(w0, pv[xx],     acc[xx]);
                    #pragma unroll
                    for (int xx = 0; xx < 8; ++xx) acc[xx] = __fmaf_rn(w1_, pv[xx + 1], acc[xx]);
                    #pragma unroll
                    for (int xx = 0; xx < 8; ++xx) acc[xx] = __fmaf_rn(w2_, pv[xx + 2], acc[xx]);
                    #pragma unroll
                    for (int xx = 0; xx < 8; ++xx) acc[xx] = __fmaf_rn(w3_, pv[xx + 3], acc[xx]);
                    #pragma unroll
                    for (int xx = 0; xx < 8; ++xx) acc[xx] = __fmaf_rn(w4_, pv[xx + 4], acc[xx]);
                }
            }
            unsigned int pb = 0;
            const unsigned int bitbase = (unsigned)((oc2 & 1) * 16 + (y2 >> 1) * 4);
            #pragma unroll
            for (int xx = 0; xx < 8; ++xx) {
                const float inp = __fmul_rn(10.0f, __fadd_rn(acc[xx], bias2));
                const float vd  = __fadd_rn(v1r[xx], __fmul_rn(CM, __fsub_rn(i1r[xx], v1r[xx])));
                const float id  = __fmul_rn(i1r[xx], CS);
                const int z = (__fsub_rn(vd, 1.0f) > 0.0f);
                v1r[xx] = z ? 0.f : vd;
                i1r[xx] = __fadd_rn(id, inp);
                if (z) pb |= 1u << (bitbase + (xx >> 1));
            }
            if (pb) atomicOr(&bm2[oc2 >> 1], pb);
        }
        __syncthreads();   // (C)

        // ===== stage3: scan2 + list2 (asc) | flagbits reset =====
        if (tid < 25) {
            int off = 0;
            for (int w = 0; w < 25; ++w) if (w < tid) off += __popc(bm2[w]);
            unsigned int bits = bm2[tid];
            if (tid == 24) nn2s = off + __popc(bits);
            while (bits) {
                const int bb = __builtin_ctz(bits);
                bits &= bits - 1;
                list2s[off++] = (unsigned short)(tid * 32 + bb);
            }
        } else if (tid >= 32 && tid < 52) {
            flagbits[tid - 32] = 0u;
        }
        __syncthreads();   // (D)

        // ===== stage4: FC(ts)+LIF3 [0..499]  ||  conv1(ts+1) [512..991]  ||  bm2 reset =====
        if (tid < 500) {
            const int nn2 = nn2s;
            const long obase = (long)tid * fc_so;
            float acc = 0.f;
            int k = 0;
            for (; k + 15 < nn2; k += 16) {
                float a[16];
                #pragma unroll
                for (int q = 0; q < 16; ++q)
                    a[q] = fcw[(long)list2s[k + q] * fc_sj + obase];
                #pragma unroll
                for (int q = 0; q < 16; ++q)
                    acc = __fmaf_rn(1.0f, a[q], acc);
            }
            for (; k < nn2; ++k)
                acc = __fmaf_rn(1.0f, fcw[(long)list2s[k] * fc_sj + obase], acc);
            const float inp = __fadd_rn(acc, bfc[tid]);
            const float vd  = __fadd_rn(v2s[tid], __fmul_rn(CM, __fsub_rn(i2s[tid], v2s[tid])));
            const float id  = __fmul_rn(i2s[tid], CS);
            const int z = (__fsub_rn(vd, 1.0f) > 0.0f);
            v2s[tid] = z ? 0.f : vd;
            i2s[tid] = __fadd_rn(id, inp);
            if (z) atomicOr(&bm3[tid >> 5], 1u << (tid & 31));
        } else if (l1) {
            if (ts + 1 < TSTEPS) conv1_step(ts + 1);
        } else if (tid >= 999 && tid < 1024) {
            bm2[tid - 999] = 0u;
        }
        __syncthreads();   // (E)

        // ===== stage5: scan3 + list3 (asc) =====
        if (tid < 16) {
            int off = 0;
            for (int w = 0; w < 16; ++w) if (w < tid) off += __popc(bm3[w]);
            unsigned int bits = bm3[tid];
            if (tid == 15) nn3s = off + __popc(bits);
            while (bits) {
                const int bb = __builtin_ctz(bits);
                bits &= bits - 1;
                list3s[off++] = (unsigned short)(tid * 32 + bb);
            }
        }
        __syncthreads();   // (F)
    }

    // epilogue: out(63)
    if (tid >= 992 && tid < 1002) {
        const int o = tid - 992;
        const int nn3 = nn3s;
        float acc = 0.f;
        int k = 0;
        for (; k + 3 < nn3; k += 4) {
            const int j0 = list3s[k],     j1 = list3s[k + 1];
            const int j2 = list3s[k + 2], j3 = list3s[k + 3];
            const float a0 = wout[o * 500 + j0];
            const float a1 = wout[o * 500 + j1];
            const float a2 = wout[o * 500 + j2];
            const float a3 = wout[o * 500 + j3];
            acc = __fmaf_rn(1.0f, a0, acc); acc = __fmaf_rn(1.0f, a1, acc);
            acc = __fmaf_rn(1.0f, a2, acc); acc = __fmaf_rn(1.0f, a3, acc);
        }
        for (; k < nn3; ++k)
            acc = __fmaf_rn(1.0f, wout[o * 500 + list3s[k]], acc);
        const float vn = __fadd_rn(vos[o], __fmul_rn(CM, __fsub_rn(ios[o], vos[o])));
        vos[o] = vn;  // ios update unnecessary (last step)
        out[((size_t)(TSTEPS - 1) * NB + b) * 10 + o] = vn;
    }
}

extern "C" void kernel_launch(void* const* d_in, const int* in_sizes, int n_in,
                              void* d_out, int out_size, void* d_ws, size_t ws_size,
                              hipStream_t stream)
{
    const float* x    = (const float*)d_in[0];
    const float* w1   = (const float*)d_in[1];
    const float* b1   = (const float*)d_in[2];
    const float* w2   = (const float*)d_in[3];
    const float* b2   = (const float*)d_in[4];
    const float* wfc  = (const float*)d_in[5];
    const float* bfc  = (const float*)d_in[6];
    const float* wout = (const float*)d_in[7];
    float* out = (float*)d_out;

    const size_t szT  = (size_t)500 * 800 * sizeof(float);       // 1.6 MB
    const size_t szW2 = (size_t)20 * 5 * 50 * 8 * sizeof(float); // 160 KB

    const float* fcptr = wfc;
    long sj = 1, so = 800;
    const float* w2rp = nullptr;
    if (ws_size >= szT) {
        float* wfcT = (float*)d_ws;
        transpose_wfc<<<(500 * 800 + 255) / 256, 256, 0, stream>>>(wfc, wfcT);
        fcptr = wfcT; sj = 500; so = 1;
        if (ws_size >= szT + szW2) {
            float* w2pad = (float*)((char*)d_ws + szT);
            pad_w2<<<(20 * 5 * 50 * 8 + 255) / 256, 256, 0, stream>>>(w2, w2pad);
            w2rp = w2pad;
        }
    }

    snn_forward<<<NB, 1024, 0, stream>>>(x, w1, b1, w2, w2rp, b2,
                                         fcptr, sj, so, bfc, wout, out);
}